// Round 7
// baseline (67.595 us; speedup 1.0000x reference)
//
#include <hip/hip_runtime.h>

typedef unsigned short u16;
typedef unsigned int u32;
typedef __bf16 bf16x8 __attribute__((ext_vector_type(8)));
typedef float f32x16 __attribute__((ext_vector_type(16)));

namespace {
constexpr int Ln = 2048;
constexpr float EPS = 1e-8f;
}

__device__ __forceinline__ u32 pk2(float lo, float hi) {
    u32 r;
    asm("v_cvt_pk_bf16_f32 %0, %1, %2" : "=v"(r) : "v"(lo), "v"(hi));
    return r;
}

// half_swap semantics: na[l<32] = b[l+32], na[l>=32] = a[l];
//                      nb[l<32] = b[l],    nb[l>=32] = a[l-32]
__device__ __forceinline__ void half_swap(u32 a, u32 b, u32& na, u32& nb) {
    u32 sa = (u32)__shfl_xor((int)a, 32, 64);
    u32 sb = (u32)__shfl_xor((int)b, 32, 64);
    int hi = (threadIdx.x & 63) >> 5;
    na = hi ? a : sb;
    nb = hi ? sa : b;
}

// ---------------- Kernel 1: projections via MFMA, no LDS (round-5, passed) --
__global__ __launch_bounds__(256) void proj_k(
    const float* __restrict__ x,
    const float* __restrict__ Bw, const float* __restrict__ Bb,
    const float* __restrict__ Cw, const float* __restrict__ Cb,
    const float* __restrict__ Vw, const float* __restrict__ Vb,
    u16* __restrict__ BZh, u16* __restrict__ CZh, u16* __restrict__ VZTh)
{
    const int tid = threadIdx.x;
    const int ln = tid & 31;
    const int g5 = (tid >> 5) & 1;
    const int w  = tid >> 6;                      // 0..3
    const int row0 = blockIdx.x * 128 + w * 32;   // flat row base of this wave

    bf16x8 wf[3][2][4];
    const float* const Wp[3] = {Bw, Cw, Vw};
    #pragma unroll
    for (int m = 0; m < 3; ++m)
      #pragma unroll
      for (int e = 0; e < 2; ++e)
        #pragma unroll
        for (int c = 0; c < 4; ++c) {
            const float* p = Wp[m] + (e * 32 + ln) * 64 + c * 16 + g5 * 8;
            const float4 lo = *(const float4*)p;
            const float4 hi = *(const float4*)(p + 4);
            uint4 t4;
            t4.x = pk2(lo.x, lo.y); t4.y = pk2(lo.z, lo.w);
            t4.z = pk2(hi.x, hi.y); t4.w = pk2(hi.z, hi.w);
            wf[m][e][c] = __builtin_bit_cast(bf16x8, t4);
        }
    bf16x8 xf[4];
    {
        const float* xp = x + (row0 + ln) * 64 + g5 * 8;
        #pragma unroll
        for (int c = 0; c < 4; ++c) {
            const float4 lo = *(const float4*)(xp + c * 16);
            const float4 hi = *(const float4*)(xp + c * 16 + 4);
            uint4 t4;
            t4.x = pk2(lo.x, lo.y); t4.y = pk2(lo.z, lo.w);
            t4.z = pk2(hi.x, hi.y); t4.w = pk2(hi.z, hi.w);
            xf[c] = __builtin_bit_cast(bf16x8, t4);
        }
    }
    const int b   = row0 >> 11;
    const int l0b = row0 & 2047;
    const float* const biasBC[2] = {Bb, Cb};
    u16* const outBC[2] = {BZh, CZh};
    #pragma unroll
    for (int m = 0; m < 2; ++m) {
        #pragma unroll
        for (int e = 0; e < 2; ++e) {
            f32x16 st;
            #pragma unroll
            for (int q = 0; q < 4; ++q) {
                const float4 bv = *(const float4*)(biasBC[m] + e * 32 + q * 8 + g5 * 4);
                st[q*4+0] = bv.x; st[q*4+1] = bv.y; st[q*4+2] = bv.z; st[q*4+3] = bv.w;
            }
            #pragma unroll
            for (int c = 0; c < 4; ++c)
                st = __builtin_amdgcn_mfma_f32_32x32x16_bf16(wf[m][e][c], xf[c], st, 0, 0, 0);
            u16* op = outBC[m] + (row0 + ln) * 64 + e * 32 + g5 * 4;
            #pragma unroll
            for (int q = 0; q < 4; ++q) {
                uint2 pk;
                pk.x = pk2(st[q*4+0], st[q*4+1]);
                pk.y = pk2(st[q*4+2], st[q*4+3]);
                *(uint2*)(op + q * 8) = pk;
            }
        }
    }
    #pragma unroll
    for (int e = 0; e < 2; ++e) {
        const float vb = Vb[e * 32 + ln];
        f32x16 st;
        #pragma unroll
        for (int r = 0; r < 16; ++r) st[r] = vb;
        #pragma unroll
        for (int c = 0; c < 4; ++c)
            st = __builtin_amdgcn_mfma_f32_32x32x16_bf16(xf[c], wf[2][e][c], st, 0, 0, 0);
        u16* op = VZTh + (b * 64 + e * 32 + ln) * Ln + l0b + g5 * 4;
        #pragma unroll
        for (int q = 0; q < 4; ++q) {
            uint2 pk;
            pk.x = pk2(st[q*4+0], st[q*4+1]);
            pk.y = pk2(st[q*4+2], st[q*4+3]);
            *(uint2*)(op + q * 8) = pk;
        }
    }
}

// ---------------- Kernel 2: column denominators, all operands direct -------
// colsum[b][m] = sum over ALL l of relu(BZ[b,l,:] . CZ[b,m,:])
// 256 blocks x 512 thr; block = (b, 64-m tile); wave (wm2 = w&1, wl4 = w>>1)
// covers its 32-m half x 512 l (wl4*32 + it*128 + ln). Barrier-free main loop.
__global__ __launch_bounds__(512) void denom_k(
    const u16* __restrict__ BZh, const u16* __restrict__ CZh,
    float* __restrict__ colsum)
{
    __shared__ float red[64][5];
    const int tid = threadIdx.x;
    const int lane = tid & 63;
    const int ln = lane & 31;
    const int g5 = lane >> 5;
    const int w = tid >> 6;
    const int wm2 = w & 1, wl4 = w >> 1;
    const int bx = (int)blockIdx.x;
    const int nf = (bx & 7) * 32 + (bx >> 3);   // XCD<->batch locality swizzle
    const int b = nf >> 5;
    const int mb = (nf & 31) * 64;

    // A-fragments: CZ rows (m) direct from global
    bf16x8 af[4];
    {
        const u16* cp = CZh + ((b * Ln + mb + wm2 * 32 + ln) << 6) + g5 * 8;
        #pragma unroll
        for (int c = 0; c < 4; ++c) af[c] = *(const bf16x8*)(cp + c * 16);
    }
    // B-fragments: BZ rows (l) direct from global; double-buffered in regs
    const u16* const bp0 = BZh + ((b * Ln + wl4 * 32 + ln) << 6) + g5 * 8;
    auto loadB = [&](int it, bf16x8* dst) {
        const u16* bp = bp0 + ((it * 128) << 6);
        #pragma unroll
        for (int c = 0; c < 4; ++c) dst[c] = *(const bf16x8*)(bp + c * 16);
    };
    bf16x8 bF[2][4];
    loadB(0, bF[0]);
    float accs[16];
    #pragma unroll
    for (int r = 0; r < 16; ++r) accs[r] = 0.f;
    #pragma unroll
    for (int it = 0; it < 16; ++it) {
        const int cur = it & 1;
        if (it < 15) loadB(it + 1, bF[cur ^ 1]);
        f32x16 st = {};
        __builtin_amdgcn_s_setprio(1);
        #pragma unroll
        for (int c = 0; c < 4; ++c)
            st = __builtin_amdgcn_mfma_f32_32x32x16_bf16(af[c], bF[cur][c], st, 0, 0, 0);
        __builtin_amdgcn_s_setprio(0);
        #pragma unroll
        for (int r = 0; r < 16; ++r) accs[r] += fmaxf(st[r], 0.f);
    }
    #pragma unroll
    for (int msk = 1; msk <= 16; msk <<= 1)
        #pragma unroll
        for (int r = 0; r < 16; ++r)
            accs[r] += __shfl_xor(accs[r], msk, 64);
    if (ln == 0) {
        #pragma unroll
        for (int r = 0; r < 16; ++r) {
            const int moff = (r & 3) + ((r >> 2) << 3) + g5 * 4;
            red[wm2 * 32 + moff][wl4] = accs[r];
        }
    }
    __syncthreads();
    if (tid < 64)
        colsum[b * Ln + mb + tid] =
            red[tid][0] + red[tid][1] + red[tid][2] + red[tid][3];
}

// ---------------- Kernel 3: S recompute + normalize + PV + residual --------
// 256 blocks x 512 thr; block = (b, 64-l tile); all MFMA operands direct from
// global (L2-hot); in-register P; LDS only for denl + epilogue reduction.
// Barrier-free main loop, reg double-buffer one chunk ahead.
__global__ __launch_bounds__(512) void fused_out(
    const float* __restrict__ x,
    const u16* __restrict__ BZh, const u16* __restrict__ CZh,
    const u16* __restrict__ VZTh, const float* __restrict__ colsum,
    float* __restrict__ out)
{
    // [0,8K) denl | [8K, 8K+6*9216=63488) red slots; lout overlaps [0,17408)
    __shared__ __attribute__((aligned(16))) char smem[63488];
    float* const denl = (float*)smem;
    const int tid = threadIdx.x;
    const int lane = tid & 63;
    const int ln = lane & 31;
    const int g5 = lane >> 5;
    const int w = tid >> 6;
    const int wm = w & 3;       // K(m)-split over 4 waves
    const int wl = w >> 2;      // l-half
    const int bx = (int)blockIdx.x;
    const int nf = (bx & 7) * 32 + (bx >> 3);   // XCD<->batch locality swizzle
    const int b = nf >> 5;
    const int l0 = (nf & 31) * 64;

    // denominators -> LDS (single barrier in the whole kernel body)
    {
        const float4 cs = *(const float4*)(colsum + b * Ln + tid * 4);
        float4 dv;
        dv.x = 1.f / (cs.x + EPS); dv.y = 1.f / (cs.y + EPS);
        dv.z = 1.f / (cs.z + EPS); dv.w = 1.f / (cs.w + EPS);
        *(float4*)(denl + tid * 4) = dv;
    }
    // BZ fragments (this block's 64 l-rows), direct
    bf16x8 bzf[4];
    {
        const u16* bp = BZh + ((b * Ln + l0 + wl * 32 + ln) << 6) + g5 * 8;
        #pragma unroll
        for (int c = 0; c < 4; ++c) bzf[c] = *(const bf16x8*)(bp + c * 16);
    }
    __syncthreads();

    // fragment load bases
    const u16* const cp0 = CZh + ((b * Ln + wm * 32 + ln) << 6) + g5 * 8;     // CZ m-rows
    const u16* const vp0 = VZTh + ((b << 6) + ln) * Ln + wm * 32 + g5 * 8;    // VZT d 0..31
    const u16* const vp1 = vp0 + (Ln << 5);                                    // VZT d 32..63

    auto loadA = [&](int t, bf16x8* dst) {
        const u16* p = cp0 + ((t * 128) << 6);
        #pragma unroll
        for (int c = 0; c < 4; ++c) dst[c] = *(const bf16x8*)(p + c * 16);
    };
    auto loadV = [&](int t, bf16x8* dst) {
        const u16* p0 = vp0 + t * 128;
        const u16* p1 = vp1 + t * 128;
        dst[0] = *(const bf16x8*)p0;          // d 0..31,  k-chunk c16=0
        dst[1] = *(const bf16x8*)(p0 + 16);   // d 0..31,  c16=1
        dst[2] = *(const bf16x8*)p1;          // d 32..63, c16=0
        dst[3] = *(const bf16x8*)(p1 + 16);   // d 32..63, c16=1
    };

    bf16x8 aF[2][4], vF[2][4];
    loadA(0, aF[0]); loadV(0, vF[0]);
    f32x16 acc0 = {}, acc1 = {};

    #pragma unroll
    for (int t = 0; t < 16; ++t) {
        const int cur = t & 1;
        if (t < 15) { loadA(t + 1, aF[cur ^ 1]); loadV(t + 1, vF[cur ^ 1]); }
        // ---- phase A: st[m][l] = CZ . BZ^T ----
        f32x16 st = {};
        __builtin_amdgcn_s_setprio(1);
        #pragma unroll
        for (int c = 0; c < 4; ++c)
            st = __builtin_amdgcn_mfma_f32_32x32x16_bf16(aF[cur][c], bzf[c], st, 0, 0, 0);
        __builtin_amdgcn_s_setprio(0);
        // ---- relu, scale by 1/den, pack ----
        const int mq0 = t * 128 + wm * 32;
        u32 wv[8];
        #pragma unroll
        for (int q = 0; q < 4; ++q) {
            const float4 dq = *(const float4*)(denl + mq0 + q * 8 + g5 * 4);
            float p0 = fmaxf(st[q*4+0], 0.f) * dq.x;
            float p1 = fmaxf(st[q*4+1], 0.f) * dq.y;
            float p2 = fmaxf(st[q*4+2], 0.f) * dq.z;
            float p3 = fmaxf(st[q*4+3], 0.f) * dq.w;
            wv[q*2+0] = pk2(p0, p1);
            wv[q*2+1] = pk2(p2, p3);
        }
        // ---- assemble PV B-fragments in-register ----
        u32 f0w0, f0w1, f0w2, f0w3, f1w0, f1w1, f1w2, f1w3;
        half_swap(wv[2], wv[0], f0w2, f0w0);
        half_swap(wv[3], wv[1], f0w3, f0w1);
        half_swap(wv[6], wv[4], f1w2, f1w0);
        half_swap(wv[7], wv[5], f1w3, f1w1);
        bf16x8 pf0, pf1;
        { uint4 t4; t4.x=f0w0; t4.y=f0w1; t4.z=f0w2; t4.w=f0w3; pf0 = __builtin_bit_cast(bf16x8, t4); }
        { uint4 t4; t4.x=f1w0; t4.y=f1w1; t4.z=f1w2; t4.w=f1w3; pf1 = __builtin_bit_cast(bf16x8, t4); }
        // ---- phase B: accT[d][l] += VZT . P over this wave's 32-m slice ----
        __builtin_amdgcn_s_setprio(1);
        acc0 = __builtin_amdgcn_mfma_f32_32x32x16_bf16(vF[cur][0], pf0, acc0, 0, 0, 0);
        acc0 = __builtin_amdgcn_mfma_f32_32x32x16_bf16(vF[cur][1], pf1, acc0, 0, 0, 0);
        acc1 = __builtin_amdgcn_mfma_f32_32x32x16_bf16(vF[cur][2], pf0, acc1, 0, 0, 0);
        acc1 = __builtin_amdgcn_mfma_f32_32x32x16_bf16(vF[cur][3], pf1, acc1, 0, 0, 0);
        __builtin_amdgcn_s_setprio(0);
    }

    // ---- cross-wave K-reduction over wm (4 waves), race-free barrier plan ----
    __syncthreads();
    float* red = (float*)(smem + 8192);
    constexpr int LSTR = 36;            // floats per lane slot (144B, bank-rotating)
    constexpr int SSTR = 64 * LSTR;     // floats per wave slot
    if (wm >= 2) {
        float* base = red + (wl * 2 + (wm - 2)) * SSTR + lane * LSTR;
        #pragma unroll
        for (int r = 0; r < 16; ++r) { base[r] = acc0[r]; base[16 + r] = acc1[r]; }
    }
    __syncthreads();
    if (wm < 2) {
        float* base = red + (wl * 2 + wm) * SSTR + lane * LSTR;
        #pragma unroll
        for (int r = 0; r < 16; ++r) { acc0[r] += base[r]; acc1[r] += base[16 + r]; }
    }
    __syncthreads();
    if (wm == 1) {
        float* base = red + (4 + wl) * SSTR + lane * LSTR;
        #pragma unroll
        for (int r = 0; r < 16; ++r) { base[r] = acc0[r]; base[16 + r] = acc1[r]; }
    }
    __syncthreads();
    float* lout = (float*)smem;         // [64 l][68 d-pad] f32; denl dead now
    if (wm == 0) {
        float* base = red + (4 + wl) * SSTR + lane * LSTR;
        #pragma unroll
        for (int r = 0; r < 16; ++r) { acc0[r] += base[r]; acc1[r] += base[16 + r]; }
        const int lrow = wl * 32 + ln;
        #pragma unroll
        for (int q = 0; q < 4; ++q) {
            const int d0 = q * 8 + g5 * 4;
            float4 v0;
            v0.x = acc0[q*4+0]; v0.y = acc0[q*4+1]; v0.z = acc0[q*4+2]; v0.w = acc0[q*4+3];
            *(float4*)(lout + lrow * 68 + d0) = v0;
            float4 v1;
            v1.x = acc1[q*4+0]; v1.y = acc1[q*4+1]; v1.z = acc1[q*4+2]; v1.w = acc1[q*4+3];
            *(float4*)(lout + lrow * 68 + 32 + d0) = v1;
        }
    }
    __syncthreads();
    {
        const int row = tid >> 3;
        const int dc = (tid & 7) * 8;
        const int g = (b * Ln + l0 + row) * 64 + dc;
        float4 o0 = *(const float4*)(lout + row * 68 + dc);
        float4 o1 = *(const float4*)(lout + row * 68 + dc + 4);
        const float4 x0 = *(const float4*)(x + g);
        const float4 x1 = *(const float4*)(x + g + 4);
        o0.x += x0.x; o0.y += x0.y; o0.z += x0.z; o0.w += x0.w;
        o1.x += x1.x; o1.y += x1.y; o1.z += x1.z; o1.w += x1.w;
        *(float4*)(out + g) = o0;
        *(float4*)(out + g + 4) = o1;
    }
}

extern "C" void kernel_launch(void* const* d_in, const int* in_sizes, int n_in,
                              void* d_out, int out_size, void* d_ws, size_t ws_size,
                              hipStream_t stream) {
    const float* x  = (const float*)d_in[0];
    const float* Bw = (const float*)d_in[1];
    const float* Bb = (const float*)d_in[2];
    const float* Cw = (const float*)d_in[3];
    const float* Cb = (const float*)d_in[4];
    const float* Vw = (const float*)d_in[5];
    const float* Vb = (const float*)d_in[6];
    float* out = (float*)d_out;
    char* wsb = (char*)d_ws;
    u16* BZh  = (u16*)wsb;                       // 2 MB
    u16* CZh  = (u16*)(wsb + (2u << 20));        // 2 MB
    u16* VZTh = (u16*)(wsb + (4u << 20));        // 2 MB
    float* colsum = (float*)(wsb + (6u << 20));  // 8 KB: [8][2048]

    proj_k<<<dim3(128), 256, 0, stream>>>(x, Bw, Bb, Cw, Cb, Vw, Vb, BZh, CZh, VZTh);
    denom_k<<<dim3(256), 512, 0, stream>>>(BZh, CZh, colsum);
    fused_out<<<dim3(256), 512, 0, stream>>>(x, BZh, CZh, VZTh, colsum, out);
}

// Round 8
// 56.568 us; speedup vs baseline: 1.1949x; 1.1949x over previous
//
#include <hip/hip_runtime.h>

typedef unsigned short u16;
typedef unsigned int u32;
typedef __bf16 bf16x8 __attribute__((ext_vector_type(8)));
typedef float f32x16 __attribute__((ext_vector_type(16)));
typedef const void __attribute__((address_space(1))) gvoid;
typedef void __attribute__((address_space(3))) lvoid;

#define GLOAD16(gp, lp) __builtin_amdgcn_global_load_lds((gvoid*)(gp), (lvoid*)(lp), 16, 0, 0)
// compiler fence after raw s_barrier: s_barrier is IntrNoMem, LDS reads may
// otherwise hoist above it and race other waves' in-flight global_load_lds.
#define POST_BARRIER_FENCE() do { __builtin_amdgcn_sched_barrier(0); asm volatile("" ::: "memory"); } while (0)

namespace {
constexpr int Ln = 2048;
constexpr float EPS = 1e-8f;
}

__device__ __forceinline__ u32 pk2(float lo, float hi) {
    u32 r;
    asm("v_cvt_pk_bf16_f32 %0, %1, %2" : "=v"(r) : "v"(lo), "v"(hi));
    return r;
}

// half_swap semantics: na[l<32] = b[l+32], na[l>=32] = a[l];
//                      nb[l<32] = b[l],    nb[l>=32] = a[l-32]
__device__ __forceinline__ void half_swap(u32 a, u32 b, u32& na, u32& nb) {
    u32 sa = (u32)__shfl_xor((int)a, 32, 64);
    u32 sb = (u32)__shfl_xor((int)b, 32, 64);
    int hi = (threadIdx.x & 63) >> 5;
    na = hi ? a : sb;
    nb = hi ? sa : b;
}

// ---------------- Kernel 1: projections via MFMA, no LDS ----------------
// 256 blocks x 128 thr (2 waves x 32 rows).
__global__ __launch_bounds__(128) void proj_k(
    const float* __restrict__ x,
    const float* __restrict__ Bw, const float* __restrict__ Bb,
    const float* __restrict__ Cw, const float* __restrict__ Cb,
    const float* __restrict__ Vw, const float* __restrict__ Vb,
    u16* __restrict__ BZh, u16* __restrict__ CZh, u16* __restrict__ VZTh)
{
    const int tid = threadIdx.x;
    const int ln = tid & 31;
    const int g5 = (tid >> 5) & 1;
    const int w  = tid >> 6;                      // 0..1
    const int row0 = blockIdx.x * 64 + w * 32;    // flat row base of this wave

    bf16x8 wf[3][2][4];
    const float* const Wp[3] = {Bw, Cw, Vw};
    #pragma unroll
    for (int m = 0; m < 3; ++m)
      #pragma unroll
      for (int e = 0; e < 2; ++e)
        #pragma unroll
        for (int c = 0; c < 4; ++c) {
            const float* p = Wp[m] + (e * 32 + ln) * 64 + c * 16 + g5 * 8;
            const float4 lo = *(const float4*)p;
            const float4 hi = *(const float4*)(p + 4);
            uint4 t4;
            t4.x = pk2(lo.x, lo.y); t4.y = pk2(lo.z, lo.w);
            t4.z = pk2(hi.x, hi.y); t4.w = pk2(hi.z, hi.w);
            wf[m][e][c] = __builtin_bit_cast(bf16x8, t4);
        }
    bf16x8 xf[4];
    {
        const float* xp = x + (row0 + ln) * 64 + g5 * 8;
        #pragma unroll
        for (int c = 0; c < 4; ++c) {
            const float4 lo = *(const float4*)(xp + c * 16);
            const float4 hi = *(const float4*)(xp + c * 16 + 4);
            uint4 t4;
            t4.x = pk2(lo.x, lo.y); t4.y = pk2(lo.z, lo.w);
            t4.z = pk2(hi.x, hi.y); t4.w = pk2(hi.z, hi.w);
            xf[c] = __builtin_bit_cast(bf16x8, t4);
        }
    }
    const int b   = row0 >> 11;
    const int l0b = row0 & 2047;
    const float* const biasBC[2] = {Bb, Cb};
    u16* const outBC[2] = {BZh, CZh};
    #pragma unroll
    for (int m = 0; m < 2; ++m) {
        #pragma unroll
        for (int e = 0; e < 2; ++e) {
            f32x16 st;
            #pragma unroll
            for (int q = 0; q < 4; ++q) {
                const float4 bv = *(const float4*)(biasBC[m] + e * 32 + q * 8 + g5 * 4);
                st[q*4+0] = bv.x; st[q*4+1] = bv.y; st[q*4+2] = bv.z; st[q*4+3] = bv.w;
            }
            #pragma unroll
            for (int c = 0; c < 4; ++c)
                st = __builtin_amdgcn_mfma_f32_32x32x16_bf16(wf[m][e][c], xf[c], st, 0, 0, 0);
            u16* op = outBC[m] + (row0 + ln) * 64 + e * 32 + g5 * 4;
            #pragma unroll
            for (int q = 0; q < 4; ++q) {
                uint2 pk;
                pk.x = pk2(st[q*4+0], st[q*4+1]);
                pk.y = pk2(st[q*4+2], st[q*4+3]);
                *(uint2*)(op + q * 8) = pk;
            }
        }
    }
    #pragma unroll
    for (int e = 0; e < 2; ++e) {
        const float vb = Vb[e * 32 + ln];
        f32x16 st;
        #pragma unroll
        for (int r = 0; r < 16; ++r) st[r] = vb;
        #pragma unroll
        for (int c = 0; c < 4; ++c)
            st = __builtin_amdgcn_mfma_f32_32x32x16_bf16(xf[c], wf[2][e][c], st, 0, 0, 0);
        u16* op = VZTh + (b * 64 + e * 32 + ln) * Ln + l0b + g5 * 4;
        #pragma unroll
        for (int q = 0; q < 4; ++q) {
            uint2 pk;
            pk.x = pk2(st[q*4+0], st[q*4+1]);
            pk.y = pk2(st[q*4+2], st[q*4+3]);
            *(uint2*)(op + q * 8) = pk;
        }
    }
}

// ---------------- Kernel 2: partial column denominators via MFMA ----------
// denp[half][b][m] = sum over l-half of relu(BZ[b,l,:] . CZ[b,m,:])
// (unchanged from round 5 — passed, ~3us)
__global__ __launch_bounds__(512) void denom_k(
    const u16* __restrict__ BZh, const u16* __restrict__ CZh,
    float* __restrict__ denp)
{
    __shared__ __attribute__((aligned(16))) char smem2[49152 + 1024];
    float* const red = (float*)(smem2 + 49152);
    const int tid = threadIdx.x;
    const int lane = tid & 63;
    const int ln = lane & 31;
    const int g5 = lane >> 5;
    const int w = tid >> 6;
    const int wm2 = w & 1, wl2 = w >> 1;     // 2 m-tiles x 4 l-subtiles
    const int flat = (int)blockIdx.z * 256 + (int)blockIdx.y * 32 + (int)blockIdx.x;
    const int nf = (flat & 7) * 64 + (flat >> 3);
    const int b = nf >> 6;
    const int rem = nf & 63;
    const int mb = (rem & 31) * 64;
    const int half = rem >> 5;
    const int l0h = half * 1024;
    const int wave_base = tid & ~63;

    bf16x8 af[4];
    {
        const u16* cp = CZh + ((b * Ln + mb + wm2 * 32 + ln) << 6) + g5 * 8;
        #pragma unroll
        for (int c = 0; c < 4; ++c) af[c] = *(const bf16x8*)(cp + c * 16);
    }
    auto stageD = [&](int t) {
        char* buf = smem2 + (t % 3) * 16384;
        #pragma unroll
        for (int it = 0; it < 2; ++it) {
            int j = (it << 9) + tid;
            int r = j >> 3;
            int u = (j & 7) ^ (r & 7);
            GLOAD16(BZh + ((b * Ln + l0h + t * 128 + r) << 6) + (u << 3),
                    buf + ((it << 9) + wave_base) * 16);
        }
    };
    stageD(0); stageD(1);
    __syncthreads();
    float accs[16];
    #pragma unroll
    for (int r = 0; r < 16; ++r) accs[r] = 0.f;
    const int lr = wl2 * 32 + ln;
    for (int t = 0; t < 8; ++t) {
        if (t > 0) {
            if (t < 7) asm volatile("s_waitcnt vmcnt(2)" ::: "memory");
            else       asm volatile("s_waitcnt vmcnt(0)" ::: "memory");
            __builtin_amdgcn_s_barrier();
            POST_BARRIER_FENCE();
        }
        if (t + 2 < 8) stageD(t + 2);
        const char* buf = smem2 + (t % 3) * 16384;
        f32x16 st = {};
        __builtin_amdgcn_s_setprio(1);
        #pragma unroll
        for (int c = 0; c < 4; ++c) {
            int un = (c << 1) | g5;
            bf16x8 bfr = *(const bf16x8*)(buf + (lr << 7) + ((un ^ (lr & 7)) << 4));
            st = __builtin_amdgcn_mfma_f32_32x32x16_bf16(af[c], bfr, st, 0, 0, 0);
        }
        __builtin_amdgcn_s_setprio(0);
        #pragma unroll
        for (int r = 0; r < 16; ++r) accs[r] += fmaxf(st[r], 0.f);
    }
    #pragma unroll
    for (int msk = 1; msk <= 16; msk <<= 1)
        #pragma unroll
        for (int r = 0; r < 16; ++r)
            accs[r] += __shfl_xor(accs[r], msk, 64);
    if (ln == 0) {
        #pragma unroll
        for (int r = 0; r < 16; ++r) {
            int mloc = wm2 * 32 + (r & 3) + ((r >> 2) << 3) + g5 * 4;
            red[mloc * 4 + wl2] = accs[r];
        }
    }
    __syncthreads();
    if (tid < 64)
        denp[(half * 8 + b) * Ln + mb + tid] =
            red[tid*4+0] + red[tid*4+1] + red[tid*4+2] + red[tid*4+3];
}

// ---------------- Kernel 3: S recompute + normalize + PV + residual --------
// CZ A-fragments direct from global (2-ahead reg dbuf); VZT LDS-staged
// (3 bufs, barrier-only loop: compiler's aF waits + in-order VMEM retirement
// guarantee staging completion 2 iterations ahead; barriers + sched fences
// pin cross-iteration order).
__global__ __launch_bounds__(512) void fused_out(
    const float* __restrict__ x,
    const u16* __restrict__ BZh, const u16* __restrict__ CZh,
    const u16* __restrict__ VZTh, const float* __restrict__ denp,
    float* __restrict__ out)
{
    // [0,8K) denl | [8K,56K) 3x16K VZT stage bufs | epilogue red = [0,55296)
    __shared__ __attribute__((aligned(16))) char smem[57344];
    float* const denl = (float*)smem;
    char* const bufs = smem + 8192;
    const int tid = threadIdx.x;
    const int lane = tid & 63;
    const int ln = lane & 31;
    const int g5 = lane >> 5;
    const int w = tid >> 6;
    const int wm = w & 3;       // m-subtile (K-split for phase B)
    const int wl = w >> 2;      // l-half
    const int bx = (int)blockIdx.x;
    const int nf = (bx & 7) * 32 + (bx >> 3);   // XCD<->batch locality swizzle
    const int b = nf >> 5;
    const int l0 = (nf & 31) * 64;
    const int wave_base = tid & ~63;

    auto stage = [&](int t) {              // VZT chunk [64 d][128 m], 16 KB
        char* vzb = bufs + (t % 3) * 16384;
        #pragma unroll
        for (int it = 0; it < 2; ++it) {
            int j = (it << 9) + tid;
            int r = j >> 4;
            int uu = (j & 15) ^ (r & 7);
            GLOAD16(VZTh + ((b << 6) + r) * Ln + (t << 7) + (uu << 3),
                    vzb + ((it << 9) + wave_base) * 16);
        }
    };
    const u16* const cp0 = CZh + ((b * Ln + wm * 32 + ln) << 6) + g5 * 8;
    auto loadA = [&](int t, bf16x8* dst) {
        const u16* p = cp0 + ((t * 128) << 6);
        #pragma unroll
        for (int c = 0; c < 4; ++c) dst[c] = *(const bf16x8*)(p + c * 16);
    };

    // prologue: denominators, BZ frags, stage 0/1, first CZ frags
    {
        const float4 c0 = *(const float4*)(denp + b * Ln + tid * 4);
        const float4 c1 = *(const float4*)(denp + (8 + b) * Ln + tid * 4);
        float4 dv;
        dv.x = 1.f / (c0.x + c1.x + EPS);
        dv.y = 1.f / (c0.y + c1.y + EPS);
        dv.z = 1.f / (c0.z + c1.z + EPS);
        dv.w = 1.f / (c0.w + c1.w + EPS);
        *(float4*)(denl + tid * 4) = dv;
    }
    bf16x8 bzf[4];
    {
        const u16* bp = BZh + ((b * Ln + l0 + wl * 32 + ln) << 6) + g5 * 8;
        #pragma unroll
        for (int c = 0; c < 4; ++c) bzf[c] = *(const bf16x8*)(bp + c * 16);
    }
    stage(0); stage(1);
    bf16x8 aF[2][4];
    loadA(0, aF[0]);
    __syncthreads();                       // full drain: stage(0/1) visible

    f32x16 acc0 = {}, acc1 = {};
    #pragma unroll
    for (int t = 0; t < 16; ++t) {
        const int cur = t & 1;
        if (t > 0) {
            __builtin_amdgcn_s_barrier();
            POST_BARRIER_FENCE();
        }
        if (t + 2 < 16) stage(t + 2);
        if (t + 1 < 16) loadA(t + 1, aF[cur ^ 1]);
        // ---- phase A: st[m][l] = CZ . BZ^T ----
        f32x16 st = {};
        __builtin_amdgcn_s_setprio(1);
        #pragma unroll
        for (int c = 0; c < 4; ++c)
            st = __builtin_amdgcn_mfma_f32_32x32x16_bf16(aF[cur][c], bzf[c], st, 0, 0, 0);
        __builtin_amdgcn_s_setprio(0);
        // ---- relu, scale by 1/den, pack ----
        const int mq0 = (t << 7) + wm * 32;
        u32 wv[8];
        #pragma unroll
        for (int q = 0; q < 4; ++q) {
            const float4 dq = *(const float4*)(denl + mq0 + q * 8 + g5 * 4);
            float p0 = fmaxf(st[q*4+0], 0.f) * dq.x;
            float p1 = fmaxf(st[q*4+1], 0.f) * dq.y;
            float p2 = fmaxf(st[q*4+2], 0.f) * dq.z;
            float p3 = fmaxf(st[q*4+3], 0.f) * dq.w;
            wv[q*2+0] = pk2(p0, p1);
            wv[q*2+1] = pk2(p2, p3);
        }
        // ---- assemble PV B-fragments in-register ----
        u32 f0w0, f0w1, f0w2, f0w3, f1w0, f1w1, f1w2, f1w3;
        half_swap(wv[2], wv[0], f0w2, f0w0);
        half_swap(wv[3], wv[1], f0w3, f0w1);
        half_swap(wv[6], wv[4], f1w2, f1w0);
        half_swap(wv[7], wv[5], f1w3, f1w1);
        bf16x8 pf0, pf1;
        { uint4 t4; t4.x=f0w0; t4.y=f0w1; t4.z=f0w2; t4.w=f0w3; pf0 = __builtin_bit_cast(bf16x8, t4); }
        { uint4 t4; t4.x=f1w0; t4.y=f1w1; t4.z=f1w2; t4.w=f1w3; pf1 = __builtin_bit_cast(bf16x8, t4); }
        // ---- phase B: accT[d][l] += VZT . P over this wave's 32-m slice ----
        const char* vz = bufs + (t % 3) * 16384;
        const int un00 = (wm << 2) | g5;            // c16 = 0
        const int un01 = (wm << 2) | 2 | g5;        // c16 = 1
        __builtin_amdgcn_s_setprio(1);
        {
            bf16x8 av;
            av = *(const bf16x8*)(vz + (ln << 8) + ((un00 ^ (ln & 7)) << 4));
            acc0 = __builtin_amdgcn_mfma_f32_32x32x16_bf16(av, pf0, acc0, 0, 0, 0);
            av = *(const bf16x8*)(vz + (ln << 8) + ((un01 ^ (ln & 7)) << 4));
            acc0 = __builtin_amdgcn_mfma_f32_32x32x16_bf16(av, pf1, acc0, 0, 0, 0);
            av = *(const bf16x8*)(vz + ((32 + ln) << 8) + ((un00 ^ (ln & 7)) << 4));
            acc1 = __builtin_amdgcn_mfma_f32_32x32x16_bf16(av, pf0, acc1, 0, 0, 0);
            av = *(const bf16x8*)(vz + ((32 + ln) << 8) + ((un01 ^ (ln & 7)) << 4));
            acc1 = __builtin_amdgcn_mfma_f32_32x32x16_bf16(av, pf1, acc1, 0, 0, 0);
        }
        __builtin_amdgcn_s_setprio(0);
    }

    // ---- epilogue: single-round cross-wm reduction + direct residual store --
    __syncthreads();                    // full drain; denl/bufs dead after this
    float* red = (float*)smem;
    constexpr int LSTR = 36;            // floats per lane slot (144B, bank-rotating)
    constexpr int SSTR = 64 * LSTR;     // 2304 floats per wave slot; 6 slots = 55296B
    if (wm != 0) {
        float* base = red + ((wm - 1) * 2 + wl) * SSTR + lane * LSTR;
        #pragma unroll
        for (int r = 0; r < 16; ++r) { base[r] = acc0[r]; base[16 + r] = acc1[r]; }
    }
    __syncthreads();
    if (wm == 0) {
        #pragma unroll
        for (int s = 0; s < 3; ++s) {
            float* base = red + (s * 2 + wl) * SSTR + lane * LSTR;
            #pragma unroll
            for (int r = 0; r < 16; ++r) { acc0[r] += base[r]; acc1[r] += base[16 + r]; }
        }
        const int row = b * Ln + l0 + wl * 32 + ln;
        #pragma unroll
        for (int q = 0; q < 4; ++q) {
            const int d0 = q * 8 + g5 * 4;
            const float4 x0 = *(const float4*)(x + row * 64 + d0);
            float4 o0;
            o0.x = x0.x + acc0[q*4+0]; o0.y = x0.y + acc0[q*4+1];
            o0.z = x0.z + acc0[q*4+2]; o0.w = x0.w + acc0[q*4+3];
            *(float4*)(out + row * 64 + d0) = o0;
            const float4 x1 = *(const float4*)(x + row * 64 + 32 + d0);
            float4 o1;
            o1.x = x1.x + acc1[q*4+0]; o1.y = x1.y + acc1[q*4+1];
            o1.z = x1.z + acc1[q*4+2]; o1.w = x1.w + acc1[q*4+3];
            *(float4*)(out + row * 64 + 32 + d0) = o1;
        }
    }
}

extern "C" void kernel_launch(void* const* d_in, const int* in_sizes, int n_in,
                              void* d_out, int out_size, void* d_ws, size_t ws_size,
                              hipStream_t stream) {
    const float* x  = (const float*)d_in[0];
    const float* Bw = (const float*)d_in[1];
    const float* Bb = (const float*)d_in[2];
    const float* Cw = (const float*)d_in[3];
    const float* Cb = (const float*)d_in[4];
    const float* Vw = (const float*)d_in[5];
    const float* Vb = (const float*)d_in[6];
    float* out = (float*)d_out;
    char* wsb = (char*)d_ws;
    u16* BZh  = (u16*)wsb;                       // 2 MB
    u16* CZh  = (u16*)(wsb + (2u << 20));        // 2 MB
    u16* VZTh = (u16*)(wsb + (4u << 20));        // 2 MB
    float* denp = (float*)(wsb + (6u << 20));    // 128 KB: [2][8][2048]

    proj_k<<<dim3(256), 128, 0, stream>>>(x, Bw, Bb, Cw, Cb, Vw, Vb, BZh, CZh, VZTh);
    denom_k<<<dim3(32, 8, 2), 512, 0, stream>>>(BZh, CZh, denp);
    fused_out<<<dim3(256), 512, 0, stream>>>(x, BZh, CZh, VZTh, denp, out);
}

// Round 10
// 50.995 us; speedup vs baseline: 1.3255x; 1.1093x over previous
//
#include <hip/hip_runtime.h>

typedef unsigned short u16;
typedef unsigned int u32;
typedef __bf16 bf16x8 __attribute__((ext_vector_type(8)));
typedef float f32x16 __attribute__((ext_vector_type(16)));
typedef const void __attribute__((address_space(1))) gvoid;
typedef void __attribute__((address_space(3))) lvoid;

#define GLOAD16(gp, lp) __builtin_amdgcn_global_load_lds((gvoid*)(gp), (lvoid*)(lp), 16, 0, 0)
// compiler fence after raw s_barrier: s_barrier is IntrNoMem, LDS reads may
// otherwise hoist above it and race other waves' in-flight global_load_lds.
#define POST_BARRIER_FENCE() do { __builtin_amdgcn_sched_barrier(0); asm volatile("" ::: "memory"); } while (0)

namespace {
constexpr int Ln = 2048;
constexpr float EPS = 1e-8f;
}

__device__ __forceinline__ u32 pk2(float lo, float hi) {
    u32 r;
    asm("v_cvt_pk_bf16_f32 %0, %1, %2" : "=v"(r) : "v"(lo), "v"(hi));
    return r;
}

// half_swap semantics: na[l<32] = b[l+32], na[l>=32] = a[l];
//                      nb[l<32] = b[l],    nb[l>=32] = a[l-32]
__device__ __forceinline__ void half_swap(u32 a, u32 b, u32& na, u32& nb) {
    u32 sa = (u32)__shfl_xor((int)a, 32, 64);
    u32 sb = (u32)__shfl_xor((int)b, 32, 64);
    int hi = (threadIdx.x & 63) >> 5;
    na = hi ? a : sb;
    nb = hi ? sa : b;
}

// ---------------- Kernel 1: projections via MFMA, no LDS (R5, passed) ------
__global__ __launch_bounds__(256) void proj_k(
    const float* __restrict__ x,
    const float* __restrict__ Bw, const float* __restrict__ Bb,
    const float* __restrict__ Cw, const float* __restrict__ Cb,
    const float* __restrict__ Vw, const float* __restrict__ Vb,
    u16* __restrict__ BZh, u16* __restrict__ CZh, u16* __restrict__ VZTh)
{
    const int tid = threadIdx.x;
    const int ln = tid & 31;
    const int g5 = (tid >> 5) & 1;
    const int w  = tid >> 6;
    const int row0 = blockIdx.x * 128 + w * 32;

    bf16x8 wf[3][2][4];
    const float* const Wp[3] = {Bw, Cw, Vw};
    #pragma unroll
    for (int m = 0; m < 3; ++m)
      #pragma unroll
      for (int e = 0; e < 2; ++e)
        #pragma unroll
        for (int c = 0; c < 4; ++c) {
            const float* p = Wp[m] + (e * 32 + ln) * 64 + c * 16 + g5 * 8;
            const float4 lo = *(const float4*)p;
            const float4 hi = *(const float4*)(p + 4);
            uint4 t4;
            t4.x = pk2(lo.x, lo.y); t4.y = pk2(lo.z, lo.w);
            t4.z = pk2(hi.x, hi.y); t4.w = pk2(hi.z, hi.w);
            wf[m][e][c] = __builtin_bit_cast(bf16x8, t4);
        }
    bf16x8 xf[4];
    {
        const float* xp = x + (row0 + ln) * 64 + g5 * 8;
        #pragma unroll
        for (int c = 0; c < 4; ++c) {
            const float4 lo = *(const float4*)(xp + c * 16);
            const float4 hi = *(const float4*)(xp + c * 16 + 4);
            uint4 t4;
            t4.x = pk2(lo.x, lo.y); t4.y = pk2(lo.z, lo.w);
            t4.z = pk2(hi.x, hi.y); t4.w = pk2(hi.z, hi.w);
            xf[c] = __builtin_bit_cast(bf16x8, t4);
        }
    }
    const int b   = row0 >> 11;
    const int l0b = row0 & 2047;
    const float* const biasBC[2] = {Bb, Cb};
    u16* const outBC[2] = {BZh, CZh};
    #pragma unroll
    for (int m = 0; m < 2; ++m) {
        #pragma unroll
        for (int e = 0; e < 2; ++e) {
            f32x16 st;
            #pragma unroll
            for (int q = 0; q < 4; ++q) {
                const float4 bv = *(const float4*)(biasBC[m] + e * 32 + q * 8 + g5 * 4);
                st[q*4+0] = bv.x; st[q*4+1] = bv.y; st[q*4+2] = bv.z; st[q*4+3] = bv.w;
            }
            #pragma unroll
            for (int c = 0; c < 4; ++c)
                st = __builtin_amdgcn_mfma_f32_32x32x16_bf16(wf[m][e][c], xf[c], st, 0, 0, 0);
            u16* op = outBC[m] + (row0 + ln) * 64 + e * 32 + g5 * 4;
            #pragma unroll
            for (int q = 0; q < 4; ++q) {
                uint2 pk;
                pk.x = pk2(st[q*4+0], st[q*4+1]);
                pk.y = pk2(st[q*4+2], st[q*4+3]);
                *(uint2*)(op + q * 8) = pk;
            }
        }
    }
    #pragma unroll
    for (int e = 0; e < 2; ++e) {
        const float vb = Vb[e * 32 + ln];
        f32x16 st;
        #pragma unroll
        for (int r = 0; r < 16; ++r) st[r] = vb;
        #pragma unroll
        for (int c = 0; c < 4; ++c)
            st = __builtin_amdgcn_mfma_f32_32x32x16_bf16(xf[c], wf[2][e][c], st, 0, 0, 0);
        u16* op = VZTh + (b * 64 + e * 32 + ln) * Ln + l0b + g5 * 4;
        #pragma unroll
        for (int q = 0; q < 4; ++q) {
            uint2 pk;
            pk.x = pk2(st[q*4+0], st[q*4+1]);
            pk.y = pk2(st[q*4+2], st[q*4+3]);
            *(uint2*)(op + q * 8) = pk;
        }
    }
}

// ---------------- Kernel 2: partial column denominators (R5, passed) -------
__global__ __launch_bounds__(512) void denom_k(
    const u16* __restrict__ BZh, const u16* __restrict__ CZh,
    float* __restrict__ denp)
{
    __shared__ __attribute__((aligned(16))) char smem2[49152 + 1024];
    float* const red = (float*)(smem2 + 49152);
    const int tid = threadIdx.x;
    const int lane = tid & 63;
    const int ln = lane & 31;
    const int g5 = lane >> 5;
    const int w = tid >> 6;
    const int wm2 = w & 1, wl2 = w >> 1;
    const int flat = (int)blockIdx.z * 256 + (int)blockIdx.y * 32 + (int)blockIdx.x;
    const int nf = (flat & 7) * 64 + (flat >> 3);
    const int b = nf >> 6;
    const int rem = nf & 63;
    const int mb = (rem & 31) * 64;
    const int half = rem >> 5;
    const int l0h = half * 1024;
    const int wave_base = tid & ~63;

    bf16x8 af[4];
    {
        const u16* cp = CZh + ((b * Ln + mb + wm2 * 32 + ln) << 6) + g5 * 8;
        #pragma unroll
        for (int c = 0; c < 4; ++c) af[c] = *(const bf16x8*)(cp + c * 16);
    }
    auto stageD = [&](int t) {
        char* buf = smem2 + (t % 3) * 16384;
        #pragma unroll
        for (int it = 0; it < 2; ++it) {
            int j = (it << 9) + tid;
            int r = j >> 3;
            int u = (j & 7) ^ (r & 7);
            GLOAD16(BZh + ((b * Ln + l0h + t * 128 + r) << 6) + (u << 3),
                    buf + ((it << 9) + wave_base) * 16);
        }
    };
    stageD(0); stageD(1);
    __syncthreads();
    float accs[16];
    #pragma unroll
    for (int r = 0; r < 16; ++r) accs[r] = 0.f;
    const int lr = wl2 * 32 + ln;
    for (int t = 0; t < 8; ++t) {
        if (t > 0) {
            if (t < 7) asm volatile("s_waitcnt vmcnt(2)" ::: "memory");
            else       asm volatile("s_waitcnt vmcnt(0)" ::: "memory");
            __builtin_amdgcn_s_barrier();
            POST_BARRIER_FENCE();
        }
        if (t + 2 < 8) stageD(t + 2);
        const char* buf = smem2 + (t % 3) * 16384;
        f32x16 st = {};
        __builtin_amdgcn_s_setprio(1);
        #pragma unroll
        for (int c = 0; c < 4; ++c) {
            int un = (c << 1) | g5;
            bf16x8 bfr = *(const bf16x8*)(buf + (lr << 7) + ((un ^ (lr & 7)) << 4));
            st = __builtin_amdgcn_mfma_f32_32x32x16_bf16(af[c], bfr, st, 0, 0, 0);
        }
        __builtin_amdgcn_s_setprio(0);
        #pragma unroll
        for (int r = 0; r < 16; ++r) accs[r] += fmaxf(st[r], 0.f);
    }
    #pragma unroll
    for (int msk = 1; msk <= 16; msk <<= 1)
        #pragma unroll
        for (int r = 0; r < 16; ++r)
            accs[r] += __shfl_xor(accs[r], msk, 64);
    if (ln == 0) {
        #pragma unroll
        for (int r = 0; r < 16; ++r) {
            int mloc = wm2 * 32 + (r & 3) + ((r >> 2) << 3) + g5 * 4;
            red[mloc * 4 + wl2] = accs[r];
        }
    }
    __syncthreads();
    if (tid < 64)
        denp[(half * 8 + b) * Ln + mb + tid] =
            red[tid*4+0] + red[tid*4+1] + red[tid*4+2] + red[tid*4+3];
}

// ---------------- Kernel 3: 256-m chunks, 8-way m-split, 2x64K dbuf --------
// 256 blocks x 512 thr; block = (b, 64-l tile). Wave wm owns m-slice
// [chunk*256 + wm*32, +32) and covers BOTH 32-l halves (A/V fragments reused
// across halves -> 1.5x less LDS read traffic, 8 barriers instead of 16).
__global__ __launch_bounds__(512) void fused_out(
    const float* __restrict__ x,
    const u16* __restrict__ BZh, const u16* __restrict__ CZh,
    const u16* __restrict__ VZTh, const float* __restrict__ denp,
    float* __restrict__ out)
{
    // [0,8K) denl | [8K,136K) 2x64K stage bufs (cz 32K + vz 32K each)
    // epilogue: red slots in bufs region (4 x 17408B)
    __shared__ __attribute__((aligned(16))) char smem[139264];
    float* const denl = (float*)smem;
    char* const bufs = smem + 8192;
    const int tid = threadIdx.x;
    const int lane = tid & 63;
    const int ln = lane & 31;
    const int g5 = lane >> 5;
    const int wm = tid >> 6;                    // 0..7: m-slice within 256-m chunk
    const int bx = (int)blockIdx.x;
    const int nf = (bx & 7) * 32 + (bx >> 3);   // XCD<->batch locality swizzle
    const int b = nf >> 5;
    const int l0 = (nf & 31) * 64;
    const int wave_base = tid & ~63;

    auto stage = [&](int t) {              // 256-m chunk: CZ [256m][64d] + VZT [64d][256m]
        char* czb = bufs + (t & 1) * 65536;
        char* vzb = czb + 32768;
        const int m0s = t << 8;
        #pragma unroll
        for (int it = 0; it < 4; ++it) {   // CZ: 2048 slots, row r=j>>3, unit u^(r&7)
            int j = (it << 9) + tid;
            int r = j >> 3;
            int u = (j & 7) ^ (r & 7);
            GLOAD16(CZh + ((b * Ln + m0s + r) << 6) + (u << 3),
                    czb + ((it << 9) + wave_base) * 16);
        }
        #pragma unroll
        for (int it = 0; it < 4; ++it) {   // VZT: 2048 slots, row r=j>>5 (512B rows)
            int j = (it << 9) + tid;
            int r = j >> 5;
            int u = (j & 31) ^ (r & 7);
            GLOAD16(VZTh + ((b << 6) + r) * Ln + m0s + (u << 3),
                    vzb + ((it << 9) + wave_base) * 16);
        }
    };

    // prologue: denominators -> LDS, BZ fragments (both l-halves) direct, stage(0)
    stage(0);
    {
        const float4 c0 = *(const float4*)(denp + b * Ln + tid * 4);
        const float4 c1 = *(const float4*)(denp + (8 + b) * Ln + tid * 4);
        float4 dv;
        dv.x = 1.f / (c0.x + c1.x + EPS);
        dv.y = 1.f / (c0.y + c1.y + EPS);
        dv.z = 1.f / (c0.z + c1.z + EPS);
        dv.w = 1.f / (c0.w + c1.w + EPS);
        *(float4*)(denl + tid * 4) = dv;
    }
    bf16x8 bzf0[4], bzf1[4];
    {
        const u16* bp0 = BZh + ((b * Ln + l0 + ln) << 6) + g5 * 8;
        const u16* bp1 = BZh + ((b * Ln + l0 + 32 + ln) << 6) + g5 * 8;
        #pragma unroll
        for (int c = 0; c < 4; ++c) {
            bzf0[c] = *(const bf16x8*)(bp0 + c * 16);
            bzf1[c] = *(const bf16x8*)(bp1 + c * 16);
        }
    }
    __syncthreads();                       // drains vmcnt: buf0 staged, denl ready

    f32x16 acc00 = {}, acc01 = {}, acc10 = {}, acc11 = {};  // [d-half][l-half]
    const int mr = wm * 32 + ln;           // CZ local row

    for (int t = 0; t < 8; ++t) {
        if (t > 0) {
            asm volatile("s_waitcnt vmcnt(0)" ::: "memory");   // stage(t) landed
            __builtin_amdgcn_s_barrier();                      // + all waves done reading buf[(t-1)&1]
            POST_BARRIER_FENCE();
        }
        if (t + 1 < 8) stage(t + 1);
        const char* czb = bufs + (t & 1) * 65536;
        const char* vzb = czb + 32768;
        // ---- A-fragments (CZ m-slice), reused for both l-halves ----
        bf16x8 a0, a1, a2, a3;
        {
            const char* base = czb + (mr << 7);
            a0 = *(const bf16x8*)(base + (((0 | g5) ^ (mr & 7)) << 4));
            a1 = *(const bf16x8*)(base + (((2 | g5) ^ (mr & 7)) << 4));
            a2 = *(const bf16x8*)(base + (((4 | g5) ^ (mr & 7)) << 4));
            a3 = *(const bf16x8*)(base + (((6 | g5) ^ (mr & 7)) << 4));
        }
        const int mq0 = (t << 8) + wm * 32;
        bf16x8 pf0h0, pf1h0, pf0h1, pf1h1;
        // ---- phase A, l-half 0 ----
        {
            f32x16 st = {};
            __builtin_amdgcn_s_setprio(1);
            st = __builtin_amdgcn_mfma_f32_32x32x16_bf16(a0, bzf0[0], st, 0, 0, 0);
            st = __builtin_amdgcn_mfma_f32_32x32x16_bf16(a1, bzf0[1], st, 0, 0, 0);
            st = __builtin_amdgcn_mfma_f32_32x32x16_bf16(a2, bzf0[2], st, 0, 0, 0);
            st = __builtin_amdgcn_mfma_f32_32x32x16_bf16(a3, bzf0[3], st, 0, 0, 0);
            __builtin_amdgcn_s_setprio(0);
            u32 wv[8];
            #pragma unroll
            for (int q = 0; q < 4; ++q) {
                const float4 dq = *(const float4*)(denl + mq0 + q * 8 + g5 * 4);
                float p0 = fmaxf(st[q*4+0], 0.f) * dq.x;
                float p1 = fmaxf(st[q*4+1], 0.f) * dq.y;
                float p2 = fmaxf(st[q*4+2], 0.f) * dq.z;
                float p3 = fmaxf(st[q*4+3], 0.f) * dq.w;
                wv[q*2+0] = pk2(p0, p1);
                wv[q*2+1] = pk2(p2, p3);
            }
            u32 f0w0, f0w1, f0w2, f0w3, f1w0, f1w1, f1w2, f1w3;
            half_swap(wv[2], wv[0], f0w2, f0w0);
            half_swap(wv[3], wv[1], f0w3, f0w1);
            half_swap(wv[6], wv[4], f1w2, f1w0);
            half_swap(wv[7], wv[5], f1w3, f1w1);
            { uint4 t4; t4.x=f0w0; t4.y=f0w1; t4.z=f0w2; t4.w=f0w3; pf0h0 = __builtin_bit_cast(bf16x8, t4); }
            { uint4 t4; t4.x=f1w0; t4.y=f1w1; t4.z=f1w2; t4.w=f1w3; pf1h0 = __builtin_bit_cast(bf16x8, t4); }
        }
        // ---- phase A, l-half 1 ----
        {
            f32x16 st = {};
            __builtin_amdgcn_s_setprio(1);
            st = __builtin_amdgcn_mfma_f32_32x32x16_bf16(a0, bzf1[0], st, 0, 0, 0);
            st = __builtin_amdgcn_mfma_f32_32x32x16_bf16(a1, bzf1[1], st, 0, 0, 0);
            st = __builtin_amdgcn_mfma_f32_32x32x16_bf16(a2, bzf1[2], st, 0, 0, 0);
            st = __builtin_amdgcn_mfma_f32_32x32x16_bf16(a3, bzf1[3], st, 0, 0, 0);
            __builtin_amdgcn_s_setprio(0);
            u32 wv[8];
            #pragma unroll
            for (int q = 0; q < 4; ++q) {
                const float4 dq = *(const float4*)(denl + mq0 + q * 8 + g5 * 4);
                float p0 = fmaxf(st[q*4+0], 0.f) * dq.x;
                float p1 = fmaxf(st[q*4+1], 0.f) * dq.y;
                float p2 = fmaxf(st[q*4+2], 0.f) * dq.z;
                float p3 = fmaxf(st[q*4+3], 0.f) * dq.w;
                wv[q*2+0] = pk2(p0, p1);
                wv[q*2+1] = pk2(p2, p3);
            }
            u32 f0w0, f0w1, f0w2, f0w3, f1w0, f1w1, f1w2, f1w3;
            half_swap(wv[2], wv[0], f0w2, f0w0);
            half_swap(wv[3], wv[1], f0w3, f0w1);
            half_swap(wv[6], wv[4], f1w2, f1w0);
            half_swap(wv[7], wv[5], f1w3, f1w1);
            { uint4 t4; t4.x=f0w0; t4.y=f0w1; t4.z=f0w2; t4.w=f0w3; pf0h1 = __builtin_bit_cast(bf16x8, t4); }
            { uint4 t4; t4.x=f1w0; t4.y=f1w1; t4.z=f1w2; t4.w=f1w3; pf1h1 = __builtin_bit_cast(bf16x8, t4); }
        }
        // ---- phase B: VZT fragments (4 reads), each reused for both l-halves ----
        // un = wm*4 + kc*2 + g5  (k-slice = m-offset within the wave's 32-m slice)
        {
            const int un0 = (wm << 2) | g5;        // kc = 0
            const int un1 = (wm << 2) | 2 | g5;    // kc = 1
            const char* r0 = vzb + (ln << 9);              // d row = ln
            const char* r1 = vzb + ((32 + ln) << 9);       // d row = 32 + ln
            bf16x8 av00 = *(const bf16x8*)(r0 + ((un0 ^ (ln & 7)) << 4));
            bf16x8 av01 = *(const bf16x8*)(r0 + ((un1 ^ (ln & 7)) << 4));
            bf16x8 av10 = *(const bf16x8*)(r1 + ((un0 ^ (ln & 7)) << 4));
            bf16x8 av11 = *(const bf16x8*)(r1 + ((un1 ^ (ln & 7)) << 4));
            __builtin_amdgcn_s_setprio(1);
            acc00 = __builtin_amdgcn_mfma_f32_32x32x16_bf16(av00, pf0h0, acc00, 0, 0, 0);
            acc00 = __builtin_amdgcn_mfma_f32_32x32x16_bf16(av01, pf1h0, acc00, 0, 0, 0);
            acc01 = __builtin_amdgcn_mfma_f32_32x32x16_bf16(av00, pf0h1, acc01, 0, 0, 0);
            acc01 = __builtin_amdgcn_mfma_f32_32x32x16_bf16(av01, pf1h1, acc01, 0, 0, 0);
            acc10 = __builtin_amdgcn_mfma_f32_32x32x16_bf16(av10, pf0h0, acc10, 0, 0, 0);
            acc10 = __builtin_amdgcn_mfma_f32_32x32x16_bf16(av11, pf1h0, acc10, 0, 0, 0);
            acc11 = __builtin_amdgcn_mfma_f32_32x32x16_bf16(av10, pf0h1, acc11, 0, 0, 0);
            acc11 = __builtin_amdgcn_mfma_f32_32x32x16_bf16(av11, pf1h1, acc11, 0, 0, 0);
            __builtin_amdgcn_s_setprio(0);
        }
    }

    // ---- epilogue: 3-round tree reduction over the 8-way m-split ----
    __syncthreads();                    // all LDS reads done; bufs dead
    float* red = (float*)bufs;
    constexpr int LSTR = 68;            // floats per lane slot
    constexpr int SSTR = 64 * LSTR;     // 4352 floats / slot; 4 slots = 69632B
    auto wslot = [&](int s) { return red + s * SSTR + lane * LSTR; };
    auto put = [&](float* p) {
        #pragma unroll
        for (int r = 0; r < 16; ++r) {
            p[r]      = acc00[r]; p[16 + r] = acc01[r];
            p[32 + r] = acc10[r]; p[48 + r] = acc11[r];
        }
    };
    auto add = [&](const float* p) {
        #pragma unroll
        for (int r = 0; r < 16; ++r) {
            acc00[r] += p[r];      acc01[r] += p[16 + r];
            acc10[r] += p[32 + r]; acc11[r] += p[48 + r];
        }
    };
    if (wm >= 4) put(wslot(wm - 4));
    __syncthreads();
    if (wm < 4) add(wslot(wm));
    __syncthreads();
    if (wm == 2 || wm == 3) put(wslot(wm - 2));
    __syncthreads();
    if (wm < 2) add(wslot(wm));
    __syncthreads();
    if (wm == 1) put(wslot(0));
    __syncthreads();
    if (wm == 0) {
        add(wslot(0));
        // lane (ln,g5) holds out^T[d = dh*32 + q*8 + g5*4 + j][l = l0 + h*32 + ln]
        #pragma unroll
        for (int h = 0; h < 2; ++h) {
            const int row = b * Ln + l0 + h * 32 + ln;
            #pragma unroll
            for (int q = 0; q < 4; ++q) {
                const int d0 = q * 8 + g5 * 4;
                const f32x16& alo = h ? acc01 : acc00;
                const f32x16& ahi = h ? acc11 : acc10;
                const float4 x0 = *(const float4*)(x + row * 64 + d0);
                float4 o0;
                o0.x = x0.x + alo[q*4+0]; o0.y = x0.y + alo[q*4+1];
                o0.z = x0.z + alo[q*4+2]; o0.w = x0.w + alo[q*4+3];
                *(float4*)(out + row * 64 + d0) = o0;
                const float4 x1 = *(const float4*)(x + row * 64 + 32 + d0);
                float4 o1;
                o1.x = x1.x + ahi[q*4+0]; o1.y = x1.y + ahi[q*4+1];
                o1.z = x1.z + ahi[q*4+2]; o1.w = x1.w + ahi[q*4+3];
                *(float4*)(out + row * 64 + 32 + d0) = o1;
            }
        }
    }
}

extern "C" void kernel_launch(void* const* d_in, const int* in_sizes, int n_in,
                              void* d_out, int out_size, void* d_ws, size_t ws_size,
                              hipStream_t stream) {
    const float* x  = (const float*)d_in[0];
    const float* Bw = (const float*)d_in[1];
    const float* Bb = (const float*)d_in[2];
    const float* Cw = (const float*)d_in[3];
    const float* Cb = (const float*)d_in[4];
    const float* Vw = (const float*)d_in[5];
    const float* Vb = (const float*)d_in[6];
    float* out = (float*)d_out;
    char* wsb = (char*)d_ws;
    u16* BZh  = (u16*)wsb;                       // 2 MB
    u16* CZh  = (u16*)(wsb + (2u << 20));        // 2 MB
    u16* VZTh = (u16*)(wsb + (4u << 20));        // 2 MB
    float* denp = (float*)(wsb + (6u << 20));    // 128 KB: [2][8][2048]

    proj_k<<<dim3(128), 256, 0, stream>>>(x, Bw, Bb, Cw, Cb, Vw, Vb, BZh, CZh, VZTh);
    denom_k<<<dim3(32, 8, 2), 512, 0, stream>>>(BZh, CZh, denp);
    fused_out<<<dim3(256), 512, 0, stream>>>(x, BZh, CZh, VZTh, denp, out);
}